// Round 8
// baseline (2028.662 us; speedup 1.0000x reference)
//
#include <hip/hip_runtime.h>
#include <hip/hip_bf16.h>

#define SEQT 2000
#define NB   2048
#define H1   51
#define MROW 16
#define NBLK (NB / MROW)   // 128 blocks, 256 threads (4 waves)
#define PADK 168           // shorts per staged row (336 B = 21*16, 16B-aligned)
#define OSTR 65            // Obuf row stride (floats) — odd, conflict-free

// log2(e) and 2*log2(e)
#define L2E  1.4426950408889634f
#define L2E2 2.8853900817779268f

typedef float f32x4 __attribute__((ext_vector_type(4)));
typedef short s16x8 __attribute__((ext_vector_type(8)));
typedef unsigned u32x4 __attribute__((ext_vector_type(4)));
typedef unsigned u32x2 __attribute__((ext_vector_type(2)));

#if __has_builtin(__builtin_amdgcn_exp2f)
#define EXP2F(x) __builtin_amdgcn_exp2f(x)
#else
#define EXP2F(x) __expf((x) * 0.6931471805599453f)   // exp(x*ln2) == 2^x
#endif

__device__ __forceinline__ short f2bf(float f) { __hip_bfloat16 b(f); return *(short*)&b; }
__device__ __forceinline__ float bf2f(short s) { __hip_bfloat16 b; *(short*)&b = s; return (float)b; }
__device__ __forceinline__ float rbf(float f) { return bf2f(f2bf(f)); }
__device__ __forceinline__ float fastrcp(float x) { return __builtin_amdgcn_rcpf(x); }
__device__ __forceinline__ float tanhfast(float x) {
    return 1.f - 2.f * fastrcp(EXP2F(x * L2E2) + 1.f);
}

__device__ __forceinline__ unsigned rne_bf16(float v) {
    unsigned b = __float_as_uint(v);
    return (b + 0x7fffu + ((b >> 16) & 1u)) >> 16;
}
// packed (hi | lo<<16), both RNE — off the hot path (x staging)
__device__ __forceinline__ unsigned pack_hilo(float v) {
    const unsigned hh = rne_bf16(v);
    const float hi = __uint_as_float(hh << 16);
    const unsigned hl = rne_bf16(v - hi);
    return hh | (hl << 16);
}

__device__ __forceinline__ f32x4 mfma16(s16x8 a, s16x8 b, f32x4 c) {
    return __builtin_amdgcn_mfma_f32_16x16x32_bf16(a, b, c, 0, 0, 0);
}

// ---------------------------------------------------------------------------
// Staged-vector column map, K=160 (5 k-tiles of 32). Columns permuted so every
// per-step write is coalesced; x and bias live inside the matmul.
//   0..95   : (h_hi,h_lo) pairs vs Whh_hi. col=(sl*4+kq)*8+2i+{0,1}, tile=sl*4+i
//   96..101 : w1 pairs (u=48+kq, kq=0..2) vs Whh_hi
//   102,103 : x_hi, x_lo vs Wih_hi
//   104..151: h_hi singles vs Whh_lo. col=104+(sl*4+kq)*4+i
//   152..154: w1 singles (u=48+kq) vs Whh_lo
//   155     : x_hi vs Wih_lo
//   156,157 : 1.0 vs bias_hi / bias_lo    158,159: 0    160..167: scratch
// EXP2 FOLD: every A-row (gate row n' = u*4+g) is pre-scaled by
//   sc(g) = -log2e (g in {i,f,o}) or -2*log2e (g == tanh gate 2),
// so e_gate = exp2(acc) directly off the MFMA accumulator.
// C/D: lane (kq,iloc) holds all 4 gates of unit u = tile*4+kq, batch row iloc.
// LSTM3 (H3=1): w1 reads C1 rows, 52-FMA dot with permuted+scaled Wz, 64-lane
// activation spread, 3x shfl_xor gate gather (no LDS), c3/h3 on lanes 0..15.
// SCHEDULING: w1 runs LSTM3(ts-1) in its hf-read-stall window (before its
// tile-12 MFMA) to balance the barrier convoy; MFMA chains are dual-acc
// (depth 3+2) to shorten the dependent-latency path.
// ---------------------------------------------------------------------------

__device__ __forceinline__ float aval(const float* __restrict__ W_hh1,
                                      const float* __restrict__ W_ih1,
                                      const float* __restrict__ b_ih1,
                                      const float* __restrict__ b_hh1,
                                      int n, float sc, bool vr, int k) {
    if (!vr) return 0.f;
    if (k < 96) {
        const int gp = k >> 3, j = k & 7;
        const int u = 4 * ((gp >> 2) * 4 + (j >> 1)) + (gp & 3);
        return rbf(sc * W_hh1[n * H1 + u]);
    } else if (k < 102) {
        const int u = 48 + ((k - 96) >> 1);
        return rbf(sc * W_hh1[n * H1 + u]);
    } else if (k < 104) {
        return rbf(sc * W_ih1[n]);               // x_hi / x_lo vs Wih_hi
    } else if (k < 152) {
        const int d = k - 104;
        const int gp = d >> 2;
        const int u = 4 * ((gp >> 2) * 4 + (d & 3)) + (gp & 3);
        const float wv = sc * W_hh1[n * H1 + u];
        return wv - rbf(wv);
    } else if (k < 155) {
        const int u = 48 + (k - 152);
        const float wv = sc * W_hh1[n * H1 + u];
        return wv - rbf(wv);
    } else if (k == 155) {
        const float wv = sc * W_ih1[n];
        return wv - rbf(wv);
    } else if (k == 156) {
        return rbf(sc * (b_ih1[n] + b_hh1[n]));
    } else if (k == 157) {
        const float bv = sc * (b_ih1[n] + b_hh1[n]);
        return bv - rbf(bv);
    }
    return 0.f;
}

template <int SL, int NTc>
__device__ __forceinline__ void run_tiles(const s16x8 (&Wfr)[4][5], const s16x8 (&hf)[5],
                                          float (&c1st)[4], short* __restrict__ Hw,
                                          float* __restrict__ C1w,
                                          const int iloc, const int kq) {
    f32x4 acc[4];
#pragma unroll
    for (int i = 0; i < NTc; ++i) {
        // dual accumulators: dependent-chain depth 3 instead of 5
        f32x4 a0 = (f32x4){0.f, 0.f, 0.f, 0.f};
        f32x4 a1 = (f32x4){0.f, 0.f, 0.f, 0.f};
        a0 = mfma16(Wfr[i][0], hf[0], a0);
        a1 = mfma16(Wfr[i][1], hf[1], a1);
        a0 = mfma16(Wfr[i][2], hf[2], a0);
        a1 = mfma16(Wfr[i][3], hf[3], a1);
        a0 = mfma16(Wfr[i][4], hf[4], a0);
        acc[i] = a0 + a1;
    }
    unsigned hp[4];
    float cl[4];
#pragma unroll
    for (int i = 0; i < NTc; ++i) {
        // acc already holds the exp2 arguments (weights pre-scaled).
        const float ei = EXP2F(acc[i][0]);        // e^{-gi}
        const float ef = EXP2F(acc[i][1]);        // e^{-gf}
        const float eg = EXP2F(acc[i][2]);        // e^{-2gg}
        const float eo = EXP2F(acc[i][3]);        // e^{-go}
        const float pf = 1.f + ef, pi_ = 1.f + ei, pg = 1.f + eg, mg = 1.f - eg;
        const float pp = pi_ * pg;
        float c1 = c1st[i];
        c1 = fmaf(c1, pp, pf * mg) * fastrcp(pf * pp);
        c1st[i] = c1;
        cl[i] = c1;
        // h1 = sig(go)*tanh(c1); clamp matches old exp-domain 80 (115.4/log2e)
        const float ec = EXP2F(fminf(115.4f, c1 * -L2E2));
        const float h1 = (1.f - ec) * fastrcp((1.f + eo) * (1.f + ec));
        // RNE hi + RNE lo via HW bf16 converts
        const __hip_bfloat16 bh(h1);
        const float df = h1 - (float)bh;
        const __hip_bfloat16 bl(df);
        hp[i] = (unsigned)*(const unsigned short*)&bh |
                ((unsigned)*(const unsigned short*)&bl << 16);
    }
    const int base = iloc * PADK;
    if (NTc == 4) {
        *(u32x4*)&Hw[base + (SL * 4 + kq) * 8] =
            (u32x4){hp[0], hp[1], hp[2], hp[3]};
        const unsigned s01 = (hp[0] & 0xffffu) | (hp[1] << 16);
        const unsigned s23 = (hp[2] & 0xffffu) | (hp[3] << 16);
        *(u32x2*)&Hw[base + 104 + (SL * 4 + kq) * 4] = (u32x2){s01, s23};
        *(f32x4*)&C1w[iloc * 52 + SL * 16 + kq * 4] =
            (f32x4){cl[0], cl[1], cl[2], cl[3]};
    } else {
        const bool ok = (48 + kq) < H1;           // kq==3 -> scratch
        *(unsigned*)&Hw[base + (ok ? 96 + 2 * kq : 160)] = hp[0];
        Hw[base + (ok ? 152 + kq : 164)] = (short)hp[0];
        C1w[iloc * 52 + 48 + kq] = cl[0];         // p=51 is scratch (Wz[51]=0)
    }
}

// Fill one 64-step x-chunk into Xbuf (wave 1, all 64 lanes), packed hi|lo.
__device__ __forceinline__ void xchunk_fill(const float* __restrict__ input, int r0, int c,
                                            int lane, unsigned (*Xb)[64 * 16]) {
    const int m = lane & 15, q = lane >> 4;
    const int tt = c * 64 + q * 16;
    f32x4 v[4];
    if (tt < SEQT) {
        const float* src = input + (size_t)(r0 + m) * SEQT + tt;
#pragma unroll
        for (int p = 0; p < 4; ++p) v[p] = *(const f32x4*)(src + 4 * p);
    } else {
#pragma unroll
        for (int p = 0; p < 4; ++p) v[p] = (f32x4){0.f, 0.f, 0.f, 0.f};
    }
#pragma unroll
    for (int p = 0; p < 4; ++p)
#pragma unroll
        for (int j = 0; j < 4; ++j)
            Xb[c & 1][(q * 16 + p * 4 + j) * 16 + m] = pack_hilo(v[p][j]);
}

__global__ void __launch_bounds__(256)
__attribute__((amdgpu_waves_per_eu(1)))
lstm_fused_kernel(const float* __restrict__ input,
                  const float* __restrict__ W_ih1,
                  const float* __restrict__ W_hh1,
                  const float* __restrict__ b_ih1,
                  const float* __restrict__ b_hh1,
                  const float* __restrict__ W_ih3,
                  const float* __restrict__ W_hh3,
                  const float* __restrict__ b_ih3,
                  const float* __restrict__ b_hh3,
                  float* __restrict__ out) {
    const int t = threadIdx.x;
    const int w = t >> 6;          // wave 0..3
    const int lane = t & 63;
    const int iloc = lane & 15, kq = lane >> 4;
    const int r0 = blockIdx.x * MROW;

    __shared__ short Hst[2][MROW * PADK];      // staged h/x/bias rows, parity dbuf
    __shared__ float C1buf[2][MROW * 52];      // raw f32 c1 (permuted u), parity dbuf
    __shared__ float Obuf[2][MROW * OSTR];     // c3 chunks
    __shared__ unsigned Xbuf[2][64 * 16];      // packed x hi/lo, 64-step chunks

    // tile assignment: w0 {0-3} SL0, w2 {4-7} SL1, w3 {8-11} SL2, w1 {12}+LSTM3+x
    const int NT = (w == 1) ? 1 : 4;
    const int tb = (w == 0) ? 0 : (w == 1) ? 12 : (w == 2) ? 4 : 8;

    // ---- gate-row weight fragments (A-operand, permuted map, exp2-scaled) ----
    s16x8 Wfr[4][5];
#pragma unroll
    for (int i = 0; i < 4; ++i) {
        if (i < NT) {
            const int np = (tb + i) * 16 + iloc;
            const int u_r = np >> 2, g_r = np & 3;
            const int n = g_r * H1 + u_r;
            const bool vr = (u_r < H1);
            const float sc = (g_r == 2) ? -L2E2 : -L2E;
#pragma unroll
            for (int kt = 0; kt < 5; ++kt) {
                s16x8 bf;
#pragma unroll
                for (int j = 0; j < 8; ++j)
                    bf[j] = f2bf(aval(W_hh1, W_ih1, b_ih1, b_hh1, n, sc, vr,
                                      kt * 32 + kq * 8 + j));
                Wfr[i][kt] = bf;
            }
        }
    }

    // ---- wave 1: LSTM3 constants (log2-scaled). lane (m,g3) ----
    const int g3 = lane >> 4;
    const float scg3 = (g3 == 2) ? L2E2 : -L2E;   // kg * log2e
    float Wz[52];
    if (w == 1) {
#pragma unroll
        for (int p = 0; p < 52; ++p) {
            const int u = (p < 48) ? (16 * (p >> 4) + 4 * (p & 3) + ((p >> 2) & 3))
                                   : p;
            Wz[p] = (u < H1) ? scg3 * W_ih3[g3 * H1 + u] : 0.f;
        }
    }
    const float whh3g = scg3 * W_hh3[g3];
    const float b3g = scg3 * (b_ih3[g3] + b_hh3[g3]);
    // activation form: act = bg + ag * rcp(exp2(pre)+1), pre already scaled
    const float ag = (g3 == 2) ? -2.f : 1.f;
    const float bg = (g3 == 2) ? 1.f : 0.f;

    // ---- LDS init ----
    for (int idx = t; idx < 2 * MROW * PADK; idx += 256)
        ((short*)Hst)[idx] = 0;
    for (int idx = t; idx < 2 * MROW * 52; idx += 256)
        ((float*)C1buf)[idx] = 0.f;
    __syncthreads();   // zeros before targeted writes
    if (t < MROW) {
        const int m = t;
#pragma unroll
        for (int p = 0; p < 2; ++p) {
            Hst[p][m * PADK + 156] = (short)0x3F80;   // 1.0 (bias cols)
            Hst[p][m * PADK + 157] = (short)0x3F80;
        }
        const float x0 = input[(size_t)(r0 + m) * SEQT];
        const unsigned xp = pack_hilo(x0);
        Hst[1][m * PADK + 102] = (short)xp;   // window 0 reads parity 1
        Hst[1][m * PADK + 103] = (short)(xp >> 16);
        Hst[1][m * PADK + 155] = (short)xp;
    }
    if (w == 1) {                 // prefill x chunks 0 and 1
        xchunk_fill(input, r0, 0, lane, Xbuf);
        xchunk_fill(input, r0, 1, lane, Xbuf);
    }
    float c1st[4] = {0.f, 0.f, 0.f, 0.f};
    float h3 = 0.f, c3 = 0.f;   // LSTM3 state (wave 1, lanes 0..15 valid)
    float h3b = 0.f;            // h3 broadcast across wave-1 lanes (per m)

#pragma unroll 1
    for (int ts = 0; ts <= SEQT; ++ts) {
        __syncthreads();
        const int rb = (ts + 1) & 1, wb = ts & 1;

        // ---- reads first: LDS read latency overlaps the rest of the step ----
        s16x8 hf[5];
        if (ts < SEQT) {
#pragma unroll
            for (int kt = 0; kt < 5; ++kt)
                hf[kt] = *(const s16x8*)&Hst[rb][iloc * PADK + kt * 32 + kq * 8];
        }
        f32x4 c1v[13];
        if (w == 1 && ts >= 1) {
            const float* cr = &C1buf[rb][(lane & 15) * 52];
#pragma unroll
            for (int j = 0; j < 13; ++j)
                c1v[j] = *(const f32x4*)(cr + 4 * j);
        }

        // ---- coalesced dump of finished 64-chunk ----
        if (ts >= 65 && (ts & 63) == 1) {
            const int c = (ts >> 6) - 1;
#pragma unroll
            for (int rep = 0; rep < 4; ++rep) {
                const int row = w + 4 * rep;
                out[(size_t)(r0 + row) * SEQT + c * 64 + lane] =
                    Obuf[c & 1][row * OSTR + lane];
            }
        }

        // ---- x chunk prefetch: issue loads early (store at step bottom) ----
        const bool fill = (w == 1) && (ts < SEQT) && ((ts & 63) == 0) &&
                          (ts >= 64) && ((ts >> 6) < 31);
        const int fc = (ts >> 6) + 1;
        f32x4 xv[4];
        if (fill) {
            const int fm = lane & 15, fq = lane >> 4;
            const int tt = fc * 64 + fq * 16;
            if (tt < SEQT) {
                const float* src = input + (size_t)(r0 + fm) * SEQT + tt;
#pragma unroll
                for (int p = 0; p < 4; ++p) xv[p] = *(const f32x4*)(src + 4 * p);
            } else {
#pragma unroll
                for (int p = 0; p < 4; ++p) xv[p] = (f32x4){0.f, 0.f, 0.f, 0.f};
            }
        }

        if (w != 1) {
            if (ts < SEQT) {
                short* Hw = &Hst[wb][0];
                float* C1w = &C1buf[wb][0];
                if (w == 0) {
                    run_tiles<0, 4>(Wfr, hf, c1st, Hw, C1w, iloc, kq);
                } else if (w == 2) {
                    run_tiles<1, 4>(Wfr, hf, c1st, Hw, C1w, iloc, kq);
                } else {
                    run_tiles<2, 4>(Wfr, hf, c1st, Hw, C1w, iloc, kq);
                }
            }
        } else {
            // ---- w1: LSTM3(ts-1) FIRST — fills the hf-read-stall window ----
            if (ts >= 1) {
                float d0 = 0.f, d1 = 0.f, d2 = 0.f, d3 = 0.f;
#pragma unroll
                for (int j = 0; j < 13; ++j) {
                    d0 = fmaf(Wz[4 * j + 0], c1v[j][0], d0);
                    d1 = fmaf(Wz[4 * j + 1], c1v[j][1], d1);
                    d2 = fmaf(Wz[4 * j + 2], c1v[j][2], d2);
                    d3 = fmaf(Wz[4 * j + 3], c1v[j][3], d3);
                }
                const float z = (d0 + d1) + (d2 + d3);
                const float pre = z + fmaf(whh3g, h3b, b3g);
                const float act = bg + ag * fastrcp(EXP2F(pre) + 1.f);
                // gather the 4 gate activations to lanes 0..15 via shfl_xor
                const float act1 = __shfl_xor(act, 16, 64);
                const float act2 = __shfl_xor(act, 32, 64);
                const float act3 = __shfl_xor(act, 48, 64);
                const int s = ts - 1;
                if (lane < MROW) {   // lanes<16: act=i, act1=f, act2=g, act3=o
                    c3 = act1 * c3 + act * act2;
                    h3 = act3 * tanhfast(c3);
                    Obuf[(s >> 6) & 1][lane * OSTR + (s & 63)] = c3;
                }
                h3b = __shfl(h3, lane & 15, 64);
            }
            if (ts < SEQT) {
                short* Hw = &Hst[wb][0];
                float* C1w = &C1buf[wb][0];
                // x staging for step ts+1 (cols 102/103/155)
                const int t1 = ts + 1;
                if (t1 < SEQT) {
                    const int m2 = lane & 15;
                    const unsigned pv = Xbuf[(t1 >> 6) & 1][(t1 & 63) * 16 + m2];
                    *(unsigned*)&Hw[m2 * PADK + 102] = pv;
                    Hw[m2 * PADK + 155] = (short)pv;
                }
                run_tiles<3, 1>(Wfr, hf, c1st, Hw, C1w, iloc, kq);
            }
        }

        // ---- x chunk prefetch: pack + store (loads had the step to land) ----
        if (fill) {
            const int fm = lane & 15, fq = lane >> 4;
#pragma unroll
            for (int p = 0; p < 4; ++p)
#pragma unroll
                for (int j = 0; j < 4; ++j)
                    Xbuf[fc & 1][(fq * 16 + p * 4 + j) * 16 + fm] =
                        pack_hilo(xv[p][j]);
        }
    }

    __syncthreads();
    // tail: steps 1984..1999 (chunk 31, parity 1)
    {
        const int row = t >> 4, pos = t & 15;
        out[(size_t)(r0 + row) * SEQT + 1984 + pos] = Obuf[1][row * OSTR + pos];
    }
}

extern "C" void kernel_launch(void* const* d_in, const int* in_sizes, int n_in,
                              void* d_out, int out_size, void* d_ws, size_t ws_size,
                              hipStream_t stream) {
    const float* input = (const float*)d_in[0];
    const float* W_ih1 = (const float*)d_in[1];
    const float* W_hh1 = (const float*)d_in[2];
    const float* b_ih1 = (const float*)d_in[3];
    const float* b_hh1 = (const float*)d_in[4];
    const float* W_ih3 = (const float*)d_in[5];
    const float* W_hh3 = (const float*)d_in[6];
    const float* b_ih3 = (const float*)d_in[7];
    const float* b_hh3 = (const float*)d_in[8];
    float* out = (float*)d_out;

    lstm_fused_kernel<<<NBLK, 256, 0, stream>>>(
        input, W_ih1, W_hh1, b_ih1, b_hh1, W_ih3, W_hh3, b_ih3, b_hh3, out);
}

// Round 9
// 2027.825 us; speedup vs baseline: 1.0004x; 1.0004x over previous
//
#include <hip/hip_runtime.h>
#include <hip/hip_bf16.h>

#define SEQT 2000
#define NB   2048
#define H1   51
#define MROW 16
#define NBLK (NB / MROW)   // 128 blocks, 256 threads (4 waves)
#define PADK 168           // shorts per staged row (336 B = 21*16, 16B-aligned)
#define OSTR 65            // Obuf row stride (floats) — odd, conflict-free

// log2(e) and 2*log2(e)
#define L2E  1.4426950408889634f
#define L2E2 2.8853900817779268f

typedef float f32x4 __attribute__((ext_vector_type(4)));
typedef short s16x8 __attribute__((ext_vector_type(8)));
typedef unsigned u32x4 __attribute__((ext_vector_type(4)));
typedef unsigned u32x2 __attribute__((ext_vector_type(2)));

#if __has_builtin(__builtin_amdgcn_exp2f)
#define EXP2F(x) __builtin_amdgcn_exp2f(x)
#else
#define EXP2F(x) __expf((x) * 0.6931471805599453f)   // exp(x*ln2) == 2^x
#endif

__device__ __forceinline__ short f2bf(float f) { __hip_bfloat16 b(f); return *(short*)&b; }
__device__ __forceinline__ float bf2f(short s) { __hip_bfloat16 b; *(short*)&b = s; return (float)b; }
__device__ __forceinline__ float rbf(float f) { return bf2f(f2bf(f)); }
__device__ __forceinline__ float fastrcp(float x) { return __builtin_amdgcn_rcpf(x); }
__device__ __forceinline__ float tanhfast(float x) {
    return 1.f - 2.f * fastrcp(EXP2F(x * L2E2) + 1.f);
}

__device__ __forceinline__ unsigned rne_bf16(float v) {
    unsigned b = __float_as_uint(v);
    return (b + 0x7fffu + ((b >> 16) & 1u)) >> 16;
}
// packed (hi | lo<<16), both RNE — off the hot path (x staging)
__device__ __forceinline__ unsigned pack_hilo(float v) {
    const unsigned hh = rne_bf16(v);
    const float hi = __uint_as_float(hh << 16);
    const unsigned hl = rne_bf16(v - hi);
    return hh | (hl << 16);
}

__device__ __forceinline__ f32x4 mfma16(s16x8 a, s16x8 b, f32x4 c) {
    return __builtin_amdgcn_mfma_f32_16x16x32_bf16(a, b, c, 0, 0, 0);
}

// ---------------------------------------------------------------------------
// Staged-vector column map, K=160 (5 k-tiles of 32). Columns permuted so every
// per-step write is coalesced; x and bias live inside the matmul.
//   0..95   : (h_hi,h_lo) pairs vs Whh_hi. col=(sl*4+kq)*8+2i+{0,1}, tile=sl*4+i
//   96..101 : w1 pairs (u=48+kq, kq=0..2) vs Whh_hi
//   102,103 : x_hi, x_lo vs Wih_hi
//   104..151: h_hi singles vs Whh_lo. col=104+(sl*4+kq)*4+i
//   152..154: w1 singles (u=48+kq) vs Whh_lo
//   155     : x_hi vs Wih_lo
//   156,157 : 1.0 vs bias_hi / bias_lo    158,159: 0    160..167: scratch
// EXP2 FOLD: every A-row (gate row n' = u*4+g) is pre-scaled by
//   sc(g) = -log2e (g in {i,f,o}) or -2*log2e (g == tanh gate 2),
// so e_gate = exp2(acc) directly off the MFMA accumulator.
// C/D: lane (kq,iloc) holds all 4 gates of unit u = tile*4+kq, batch row iloc.
// LSTM3 (H3=1): w1 reads C1 rows (latency hidden under its tile-12 compute),
// 52-FMA dot (8 accumulators), 64-lane activation spread, 3x shfl_xor gate
// gather (no LDS), c3/h3 on lanes 0..15.
// STRAGGLER BALANCE (r7 lesson: w1 is the barrier straggler): LSTM3 stays at
// w1's step END (c1v latency hidden under tile-12); x-staging moved to w2;
// Ztr LDS roundtrip replaced by shfl; dual-acc MFMA chains (depth 3+2).
// ---------------------------------------------------------------------------

__device__ __forceinline__ float aval(const float* __restrict__ W_hh1,
                                      const float* __restrict__ W_ih1,
                                      const float* __restrict__ b_ih1,
                                      const float* __restrict__ b_hh1,
                                      int n, float sc, bool vr, int k) {
    if (!vr) return 0.f;
    if (k < 96) {
        const int gp = k >> 3, j = k & 7;
        const int u = 4 * ((gp >> 2) * 4 + (j >> 1)) + (gp & 3);
        return rbf(sc * W_hh1[n * H1 + u]);
    } else if (k < 102) {
        const int u = 48 + ((k - 96) >> 1);
        return rbf(sc * W_hh1[n * H1 + u]);
    } else if (k < 104) {
        return rbf(sc * W_ih1[n]);               // x_hi / x_lo vs Wih_hi
    } else if (k < 152) {
        const int d = k - 104;
        const int gp = d >> 2;
        const int u = 4 * ((gp >> 2) * 4 + (d & 3)) + (gp & 3);
        const float wv = sc * W_hh1[n * H1 + u];
        return wv - rbf(wv);
    } else if (k < 155) {
        const int u = 48 + (k - 152);
        const float wv = sc * W_hh1[n * H1 + u];
        return wv - rbf(wv);
    } else if (k == 155) {
        const float wv = sc * W_ih1[n];
        return wv - rbf(wv);
    } else if (k == 156) {
        return rbf(sc * (b_ih1[n] + b_hh1[n]));
    } else if (k == 157) {
        const float bv = sc * (b_ih1[n] + b_hh1[n]);
        return bv - rbf(bv);
    }
    return 0.f;
}

template <int SL, int NTc>
__device__ __forceinline__ void run_tiles(const s16x8 (&Wfr)[4][5], const s16x8 (&hf)[5],
                                          float (&c1st)[4], short* __restrict__ Hw,
                                          float* __restrict__ C1w,
                                          const int iloc, const int kq) {
    f32x4 acc[4];
#pragma unroll
    for (int i = 0; i < NTc; ++i) {
        // dual accumulators: dependent-chain depth 3 instead of 5
        f32x4 a0 = (f32x4){0.f, 0.f, 0.f, 0.f};
        f32x4 a1 = (f32x4){0.f, 0.f, 0.f, 0.f};
        a0 = mfma16(Wfr[i][0], hf[0], a0);
        a1 = mfma16(Wfr[i][1], hf[1], a1);
        a0 = mfma16(Wfr[i][2], hf[2], a0);
        a1 = mfma16(Wfr[i][3], hf[3], a1);
        a0 = mfma16(Wfr[i][4], hf[4], a0);
        acc[i] = a0 + a1;
    }
    unsigned hp[4];
    float cl[4];
#pragma unroll
    for (int i = 0; i < NTc; ++i) {
        // acc already holds the exp2 arguments (weights pre-scaled).
        const float ei = EXP2F(acc[i][0]);        // e^{-gi}
        const float ef = EXP2F(acc[i][1]);        // e^{-gf}
        const float eg = EXP2F(acc[i][2]);        // e^{-2gg}
        const float eo = EXP2F(acc[i][3]);        // e^{-go}
        const float pf = 1.f + ef, pi_ = 1.f + ei, pg = 1.f + eg, mg = 1.f - eg;
        const float pp = pi_ * pg;
        float c1 = c1st[i];
        c1 = fmaf(c1, pp, pf * mg) * fastrcp(pf * pp);
        c1st[i] = c1;
        cl[i] = c1;
        // h1 = sig(go)*tanh(c1); clamp matches old exp-domain 80 (115.4/log2e)
        const float ec = EXP2F(fminf(115.4f, c1 * -L2E2));
        const float h1 = (1.f - ec) * fastrcp((1.f + eo) * (1.f + ec));
        // RNE hi + RNE lo via HW bf16 converts
        const __hip_bfloat16 bh(h1);
        const float df = h1 - (float)bh;
        const __hip_bfloat16 bl(df);
        hp[i] = (unsigned)*(const unsigned short*)&bh |
                ((unsigned)*(const unsigned short*)&bl << 16);
    }
    const int base = iloc * PADK;
    if (NTc == 4) {
        *(u32x4*)&Hw[base + (SL * 4 + kq) * 8] =
            (u32x4){hp[0], hp[1], hp[2], hp[3]};
        const unsigned s01 = (hp[0] & 0xffffu) | (hp[1] << 16);
        const unsigned s23 = (hp[2] & 0xffffu) | (hp[3] << 16);
        *(u32x2*)&Hw[base + 104 + (SL * 4 + kq) * 4] = (u32x2){s01, s23};
        *(f32x4*)&C1w[iloc * 52 + SL * 16 + kq * 4] =
            (f32x4){cl[0], cl[1], cl[2], cl[3]};
    } else {
        const bool ok = (48 + kq) < H1;           // kq==3 -> scratch
        *(unsigned*)&Hw[base + (ok ? 96 + 2 * kq : 160)] = hp[0];
        Hw[base + (ok ? 152 + kq : 164)] = (short)hp[0];
        C1w[iloc * 52 + 48 + kq] = cl[0];         // p=51 is scratch (Wz[51]=0)
    }
}

// Fill one 64-step x-chunk into Xbuf (wave 1, all 64 lanes), packed hi|lo.
__device__ __forceinline__ void xchunk_fill(const float* __restrict__ input, int r0, int c,
                                            int lane, unsigned (*Xb)[64 * 16]) {
    const int m = lane & 15, q = lane >> 4;
    const int tt = c * 64 + q * 16;
    f32x4 v[4];
    if (tt < SEQT) {
        const float* src = input + (size_t)(r0 + m) * SEQT + tt;
#pragma unroll
        for (int p = 0; p < 4; ++p) v[p] = *(const f32x4*)(src + 4 * p);
    } else {
#pragma unroll
        for (int p = 0; p < 4; ++p) v[p] = (f32x4){0.f, 0.f, 0.f, 0.f};
    }
#pragma unroll
    for (int p = 0; p < 4; ++p)
#pragma unroll
        for (int j = 0; j < 4; ++j)
            Xb[c & 1][(q * 16 + p * 4 + j) * 16 + m] = pack_hilo(v[p][j]);
}

__global__ void __launch_bounds__(256)
__attribute__((amdgpu_waves_per_eu(1)))
lstm_fused_kernel(const float* __restrict__ input,
                  const float* __restrict__ W_ih1,
                  const float* __restrict__ W_hh1,
                  const float* __restrict__ b_ih1,
                  const float* __restrict__ b_hh1,
                  const float* __restrict__ W_ih3,
                  const float* __restrict__ W_hh3,
                  const float* __restrict__ b_ih3,
                  const float* __restrict__ b_hh3,
                  float* __restrict__ out) {
    const int t = threadIdx.x;
    const int w = t >> 6;          // wave 0..3
    const int lane = t & 63;
    const int iloc = lane & 15, kq = lane >> 4;
    const int r0 = blockIdx.x * MROW;

    __shared__ short Hst[2][MROW * PADK];      // staged h/x/bias rows, parity dbuf
    __shared__ float C1buf[2][MROW * 52];      // raw f32 c1 (permuted u), parity dbuf
    __shared__ float Obuf[2][MROW * OSTR];     // c3 chunks
    __shared__ unsigned Xbuf[2][64 * 16];      // packed x hi/lo, 64-step chunks

    // tile assignment: w0 {0-3} SL0, w2 {4-7} SL1 + x, w3 {8-11} SL2,
    // w1 {12} + LSTM3 (straggler-trimmed)
    const int NT = (w == 1) ? 1 : 4;
    const int tb = (w == 0) ? 0 : (w == 1) ? 12 : (w == 2) ? 4 : 8;

    // ---- gate-row weight fragments (A-operand, permuted map, exp2-scaled) ----
    s16x8 Wfr[4][5];
#pragma unroll
    for (int i = 0; i < 4; ++i) {
        if (i < NT) {
            const int np = (tb + i) * 16 + iloc;
            const int u_r = np >> 2, g_r = np & 3;
            const int n = g_r * H1 + u_r;
            const bool vr = (u_r < H1);
            const float sc = (g_r == 2) ? -L2E2 : -L2E;
#pragma unroll
            for (int kt = 0; kt < 5; ++kt) {
                s16x8 bf;
#pragma unroll
                for (int j = 0; j < 8; ++j)
                    bf[j] = f2bf(aval(W_hh1, W_ih1, b_ih1, b_hh1, n, sc, vr,
                                      kt * 32 + kq * 8 + j));
                Wfr[i][kt] = bf;
            }
        }
    }

    // ---- wave 1: LSTM3 constants (log2-scaled). lane (m,g3) ----
    const int g3 = lane >> 4;
    const float scg3 = (g3 == 2) ? L2E2 : -L2E;   // kg * log2e
    float Wz[52];
    if (w == 1) {
#pragma unroll
        for (int p = 0; p < 52; ++p) {
            const int u = (p < 48) ? (16 * (p >> 4) + 4 * (p & 3) + ((p >> 2) & 3))
                                   : p;
            Wz[p] = (u < H1) ? scg3 * W_ih3[g3 * H1 + u] : 0.f;
        }
    }
    const float whh3g = scg3 * W_hh3[g3];
    const float b3g = scg3 * (b_ih3[g3] + b_hh3[g3]);
    // activation form: act = bg + ag * rcp(exp2(pre)+1), pre already scaled
    const float ag = (g3 == 2) ? -2.f : 1.f;
    const float bg = (g3 == 2) ? 1.f : 0.f;

    // ---- LDS init ----
    for (int idx = t; idx < 2 * MROW * PADK; idx += 256)
        ((short*)Hst)[idx] = 0;
    for (int idx = t; idx < 2 * MROW * 52; idx += 256)
        ((float*)C1buf)[idx] = 0.f;
    __syncthreads();   // zeros before targeted writes
    if (t < MROW) {
        const int m = t;
#pragma unroll
        for (int p = 0; p < 2; ++p) {
            Hst[p][m * PADK + 156] = (short)0x3F80;   // 1.0 (bias cols)
            Hst[p][m * PADK + 157] = (short)0x3F80;
        }
        const float x0 = input[(size_t)(r0 + m) * SEQT];
        const unsigned xp = pack_hilo(x0);
        Hst[1][m * PADK + 102] = (short)xp;   // window 0 reads parity 1
        Hst[1][m * PADK + 103] = (short)(xp >> 16);
        Hst[1][m * PADK + 155] = (short)xp;
    }
    if (w == 1) {                 // prefill x chunks 0 and 1 (w2 reads after barrier)
        xchunk_fill(input, r0, 0, lane, Xbuf);
        xchunk_fill(input, r0, 1, lane, Xbuf);
    }
    float c1st[4] = {0.f, 0.f, 0.f, 0.f};
    float h3 = 0.f, c3 = 0.f;   // LSTM3 state (wave 1, lanes 0..15 valid)
    float h3b = 0.f;            // h3 broadcast across wave-1 lanes (per m)

#pragma unroll 1
    for (int ts = 0; ts <= SEQT; ++ts) {
        __syncthreads();
        const int rb = (ts + 1) & 1, wb = ts & 1;

        // ---- reads first: LDS read latency overlaps the rest of the step ----
        s16x8 hf[5];
        if (ts < SEQT) {
#pragma unroll
            for (int kt = 0; kt < 5; ++kt)
                hf[kt] = *(const s16x8*)&Hst[rb][iloc * PADK + kt * 32 + kq * 8];
        }
        f32x4 c1v[13];
        if (w == 1 && ts >= 1) {
            const float* cr = &C1buf[rb][(lane & 15) * 52];
#pragma unroll
            for (int j = 0; j < 13; ++j)
                c1v[j] = *(const f32x4*)(cr + 4 * j);
        }

        // ---- coalesced dump of finished 64-chunk ----
        if (ts >= 65 && (ts & 63) == 1) {
            const int c = (ts >> 6) - 1;
#pragma unroll
            for (int rep = 0; rep < 4; ++rep) {
                const int row = w + 4 * rep;
                out[(size_t)(r0 + row) * SEQT + c * 64 + lane] =
                    Obuf[c & 1][row * OSTR + lane];
            }
        }

        // ---- x chunk prefetch: issue loads early (store at step bottom) ----
        const bool fill = (w == 1) && (ts < SEQT) && ((ts & 63) == 0) &&
                          (ts >= 64) && ((ts >> 6) < 31);
        const int fc = (ts >> 6) + 1;
        f32x4 xv[4];
        if (fill) {
            const int fm = lane & 15, fq = lane >> 4;
            const int tt = fc * 64 + fq * 16;
            if (tt < SEQT) {
                const float* src = input + (size_t)(r0 + fm) * SEQT + tt;
#pragma unroll
                for (int p = 0; p < 4; ++p) xv[p] = *(const f32x4*)(src + 4 * p);
            } else {
#pragma unroll
                for (int p = 0; p < 4; ++p) xv[p] = (f32x4){0.f, 0.f, 0.f, 0.f};
            }
        }

        if (ts < SEQT) {
            short* Hw = &Hst[wb][0];
            float* C1w = &C1buf[wb][0];
            if (w == 0) {
                run_tiles<0, 4>(Wfr, hf, c1st, Hw, C1w, iloc, kq);
            } else if (w == 2) {
                // x staging for step ts+1 (cols 102/103/155) — moved off w1
                const int t1 = ts + 1;
                if (t1 < SEQT) {
                    const int m2 = lane & 15;
                    const unsigned pv = Xbuf[(t1 >> 6) & 1][(t1 & 63) * 16 + m2];
                    *(unsigned*)&Hw[m2 * PADK + 102] = pv;
                    Hw[m2 * PADK + 155] = (short)pv;
                }
                run_tiles<1, 4>(Wfr, hf, c1st, Hw, C1w, iloc, kq);
            } else if (w == 3) {
                run_tiles<2, 4>(Wfr, hf, c1st, Hw, C1w, iloc, kq);
            } else {
                run_tiles<3, 1>(Wfr, hf, c1st, Hw, C1w, iloc, kq);
            }
        }

        // ---- LSTM3 for step ts-1 (wave 1, AFTER its tile: c1v latency hidden).
        //      8-acc dot + shfl gate gather (no LDS roundtrip). ----
        if (w == 1 && ts >= 1) {
            float d0a = 0.f, d1a = 0.f, d2a = 0.f, d3a = 0.f;
            float d0b = 0.f, d1b = 0.f, d2b = 0.f, d3b = 0.f;
#pragma unroll
            for (int j = 0; j < 13; ++j) {
                if ((j & 1) == 0) {
                    d0a = fmaf(Wz[4 * j + 0], c1v[j][0], d0a);
                    d1a = fmaf(Wz[4 * j + 1], c1v[j][1], d1a);
                    d2a = fmaf(Wz[4 * j + 2], c1v[j][2], d2a);
                    d3a = fmaf(Wz[4 * j + 3], c1v[j][3], d3a);
                } else {
                    d0b = fmaf(Wz[4 * j + 0], c1v[j][0], d0b);
                    d1b = fmaf(Wz[4 * j + 1], c1v[j][1], d1b);
                    d2b = fmaf(Wz[4 * j + 2], c1v[j][2], d2b);
                    d3b = fmaf(Wz[4 * j + 3], c1v[j][3], d3b);
                }
            }
            const float z = ((d0a + d0b) + (d1a + d1b)) +
                            ((d2a + d2b) + (d3a + d3b));
            const float pre = z + fmaf(whh3g, h3b, b3g);
            const float act = bg + ag * fastrcp(EXP2F(pre) + 1.f);
            // gather the 4 gate activations to lanes 0..15 via shfl_xor (exact)
            const float act1 = __shfl_xor(act, 16, 64);
            const float act2 = __shfl_xor(act, 32, 64);
            const float act3 = __shfl_xor(act, 48, 64);
            const int s = ts - 1;
            if (lane < MROW) {   // lanes<16: act=i, act1=f, act2=g, act3=o
                c3 = act1 * c3 + act * act2;
                h3 = act3 * tanhfast(c3);
                Obuf[(s >> 6) & 1][lane * OSTR + (s & 63)] = c3;
            }
            h3b = __shfl(h3, lane & 15, 64);
        }

        // ---- x chunk prefetch: pack + store (loads had the step to land) ----
        if (fill) {
            const int fm = lane & 15, fq = lane >> 4;
#pragma unroll
            for (int p = 0; p < 4; ++p)
#pragma unroll
                for (int j = 0; j < 4; ++j)
                    Xbuf[fc & 1][(fq * 16 + p * 4 + j) * 16 + fm] =
                        pack_hilo(xv[p][j]);
        }
    }

    __syncthreads();
    // tail: steps 1984..1999 (chunk 31, parity 1)
    {
        const int row = t >> 4, pos = t & 15;
        out[(size_t)(r0 + row) * SEQT + 1984 + pos] = Obuf[1][row * OSTR + pos];
    }
}

extern "C" void kernel_launch(void* const* d_in, const int* in_sizes, int n_in,
                              void* d_out, int out_size, void* d_ws, size_t ws_size,
                              hipStream_t stream) {
    const float* input = (const float*)d_in[0];
    const float* W_ih1 = (const float*)d_in[1];
    const float* W_hh1 = (const float*)d_in[2];
    const float* b_ih1 = (const float*)d_in[3];
    const float* b_hh1 = (const float*)d_in[4];
    const float* W_ih3 = (const float*)d_in[5];
    const float* W_hh3 = (const float*)d_in[6];
    const float* b_ih3 = (const float*)d_in[7];
    const float* b_hh3 = (const float*)d_in[8];
    float* out = (float*)d_out;

    lstm_fused_kernel<<<NBLK, 256, 0, stream>>>(
        input, W_ih1, W_hh1, b_ih1, b_hh1, W_ih3, W_hh3, b_ih3, b_hh3, out);
}

// Round 10
// 1905.408 us; speedup vs baseline: 1.0647x; 1.0642x over previous
//
#include <hip/hip_runtime.h>
#include <hip/hip_bf16.h>

#define SEQT 2000
#define NB   2048
#define H1   51
#define MROW 16
#define NBLK (NB / MROW)   // 128 blocks, 256 threads (4 waves)
#define PADK 168           // shorts per staged row (336 B = 21*16, 16B-aligned)
#define OSTR 65            // Obuf row stride (floats) — odd, conflict-free

// log2(e) and 2*log2(e)
#define L2E  1.4426950408889634f
#define L2E2 2.8853900817779268f

typedef float f32x4 __attribute__((ext_vector_type(4)));
typedef short s16x8 __attribute__((ext_vector_type(8)));
typedef unsigned u32x4 __attribute__((ext_vector_type(4)));
typedef unsigned u32x2 __attribute__((ext_vector_type(2)));

#if __has_builtin(__builtin_amdgcn_exp2f)
#define EXP2F(x) __builtin_amdgcn_exp2f(x)
#else
#define EXP2F(x) __expf((x) * 0.6931471805599453f)   // exp(x*ln2) == 2^x
#endif

__device__ __forceinline__ short f2bf(float f) { __hip_bfloat16 b(f); return *(short*)&b; }
__device__ __forceinline__ float bf2f(short s) { __hip_bfloat16 b; *(short*)&b = s; return (float)b; }
__device__ __forceinline__ float rbf(float f) { return bf2f(f2bf(f)); }
__device__ __forceinline__ float fastrcp(float x) { return __builtin_amdgcn_rcpf(x); }
__device__ __forceinline__ float tanhfast(float x) {
    return 1.f - 2.f * fastrcp(EXP2F(x * L2E2) + 1.f);
}

__device__ __forceinline__ unsigned rne_bf16(float v) {
    unsigned b = __float_as_uint(v);
    return (b + 0x7fffu + ((b >> 16) & 1u)) >> 16;
}
// packed (hi | lo<<16), both RNE — off the hot path (x staging)
__device__ __forceinline__ unsigned pack_hilo(float v) {
    const unsigned hh = rne_bf16(v);
    const float hi = __uint_as_float(hh << 16);
    const unsigned hl = rne_bf16(v - hi);
    return hh | (hl << 16);
}

__device__ __forceinline__ f32x4 mfma16(s16x8 a, s16x8 b, f32x4 c) {
    return __builtin_amdgcn_mfma_f32_16x16x32_bf16(a, b, c, 0, 0, 0);
}

// ---------------------------------------------------------------------------
// Staged-vector column map, K=160 (5 k-tiles of 32). Columns permuted so every
// per-step write is coalesced; x and bias live inside the matmul.
//   0..95   : (h_hi,h_lo) pairs vs Whh_hi. col=(sl*4+kq)*8+2i+{0,1}, tile=sl*4+i
//   96..101 : w1 pairs (u=48+kq, kq=0..2) vs Whh_hi
//   102,103 : x_hi, x_lo vs Wih_hi
//   104..151: h_hi singles vs Whh_lo. col=104+(sl*4+kq)*4+i
//   152..154: w1 singles (u=48+kq) vs Whh_lo
//   155     : x_hi vs Wih_lo
//   156,157 : 1.0 vs bias_hi / bias_lo    158,159: 0    160..167: scratch
// EXP2 FOLD: every A-row (gate row n' = u*4+g) is pre-scaled by
//   sc(g) = -log2e (g in {i,f,o}) or -2*log2e (g == tanh gate 2),
// so e_gate = exp2(acc) directly off the MFMA accumulator.
// C/D: lane (kq,iloc) holds all 4 gates of unit u = tile*4+kq, batch row iloc.
// MFMA: SINGLE-accumulator chains (r7/r8 A/B: dual-acc + join-add costs
// ~150 cy/step — the 4 independent tiles already pipeline the MFMA latency).
// LSTM3 (H3=1): w1 reads C1 rows (latency hidden under its tile-12 compute),
// 52-FMA dot (8 accumulators), 64-lane activation spread, 3x shfl_xor gate
// gather (no LDS roundtrip), c3/h3 on lanes 0..15.
// STRAGGLER BALANCE (r7: w1 is the barrier straggler): LSTM3 at w1's step END;
// x-staging on w2; Ztr LDS roundtrip replaced by shfl.
// ---------------------------------------------------------------------------

__device__ __forceinline__ float aval(const float* __restrict__ W_hh1,
                                      const float* __restrict__ W_ih1,
                                      const float* __restrict__ b_ih1,
                                      const float* __restrict__ b_hh1,
                                      int n, float sc, bool vr, int k) {
    if (!vr) return 0.f;
    if (k < 96) {
        const int gp = k >> 3, j = k & 7;
        const int u = 4 * ((gp >> 2) * 4 + (j >> 1)) + (gp & 3);
        return rbf(sc * W_hh1[n * H1 + u]);
    } else if (k < 102) {
        const int u = 48 + ((k - 96) >> 1);
        return rbf(sc * W_hh1[n * H1 + u]);
    } else if (k < 104) {
        return rbf(sc * W_ih1[n]);               // x_hi / x_lo vs Wih_hi
    } else if (k < 152) {
        const int d = k - 104;
        const int gp = d >> 2;
        const int u = 4 * ((gp >> 2) * 4 + (d & 3)) + (gp & 3);
        const float wv = sc * W_hh1[n * H1 + u];
        return wv - rbf(wv);
    } else if (k < 155) {
        const int u = 48 + (k - 152);
        const float wv = sc * W_hh1[n * H1 + u];
        return wv - rbf(wv);
    } else if (k == 155) {
        const float wv = sc * W_ih1[n];
        return wv - rbf(wv);
    } else if (k == 156) {
        return rbf(sc * (b_ih1[n] + b_hh1[n]));
    } else if (k == 157) {
        const float bv = sc * (b_ih1[n] + b_hh1[n]);
        return bv - rbf(bv);
    }
    return 0.f;
}

template <int SL, int NTc>
__device__ __forceinline__ void run_tiles(const s16x8 (&Wfr)[4][5], const s16x8 (&hf)[5],
                                          float (&c1st)[4], short* __restrict__ Hw,
                                          float* __restrict__ C1w,
                                          const int iloc, const int kq) {
    f32x4 acc[4];
#pragma unroll
    for (int i = 0; i < NTc; ++i) {
        // single accumulator chain (4 independent tiles pipeline the latency)
        f32x4 a = (f32x4){0.f, 0.f, 0.f, 0.f};
        a = mfma16(Wfr[i][0], hf[0], a);
        a = mfma16(Wfr[i][1], hf[1], a);
        a = mfma16(Wfr[i][2], hf[2], a);
        a = mfma16(Wfr[i][3], hf[3], a);
        a = mfma16(Wfr[i][4], hf[4], a);
        acc[i] = a;
    }
    unsigned hp[4];
    float cl[4];
#pragma unroll
    for (int i = 0; i < NTc; ++i) {
        // acc already holds the exp2 arguments (weights pre-scaled).
        const float ei = EXP2F(acc[i][0]);        // e^{-gi}
        const float ef = EXP2F(acc[i][1]);        // e^{-gf}
        const float eg = EXP2F(acc[i][2]);        // e^{-2gg}
        const float eo = EXP2F(acc[i][3]);        // e^{-go}
        const float pf = 1.f + ef, pi_ = 1.f + ei, pg = 1.f + eg, mg = 1.f - eg;
        const float pp = pi_ * pg;
        float c1 = c1st[i];
        c1 = fmaf(c1, pp, pf * mg) * fastrcp(pf * pp);
        c1st[i] = c1;
        cl[i] = c1;
        // h1 = sig(go)*tanh(c1); clamp matches old exp-domain 80 (115.4/log2e)
        const float ec = EXP2F(fminf(115.4f, c1 * -L2E2));
        const float h1 = (1.f - ec) * fastrcp((1.f + eo) * (1.f + ec));
        // RNE hi + RNE lo via HW bf16 converts
        const __hip_bfloat16 bh(h1);
        const float df = h1 - (float)bh;
        const __hip_bfloat16 bl(df);
        hp[i] = (unsigned)*(const unsigned short*)&bh |
                ((unsigned)*(const unsigned short*)&bl << 16);
    }
    const int base = iloc * PADK;
    if (NTc == 4) {
        *(u32x4*)&Hw[base + (SL * 4 + kq) * 8] =
            (u32x4){hp[0], hp[1], hp[2], hp[3]};
        const unsigned s01 = (hp[0] & 0xffffu) | (hp[1] << 16);
        const unsigned s23 = (hp[2] & 0xffffu) | (hp[3] << 16);
        *(u32x2*)&Hw[base + 104 + (SL * 4 + kq) * 4] = (u32x2){s01, s23};
        *(f32x4*)&C1w[iloc * 52 + SL * 16 + kq * 4] =
            (f32x4){cl[0], cl[1], cl[2], cl[3]};
    } else {
        const bool ok = (48 + kq) < H1;           // kq==3 -> scratch
        *(unsigned*)&Hw[base + (ok ? 96 + 2 * kq : 160)] = hp[0];
        Hw[base + (ok ? 152 + kq : 164)] = (short)hp[0];
        C1w[iloc * 52 + 48 + kq] = cl[0];         // p=51 is scratch (Wz[51]=0)
    }
}

// Fill one 64-step x-chunk into Xbuf (wave 1, all 64 lanes), packed hi|lo.
__device__ __forceinline__ void xchunk_fill(const float* __restrict__ input, int r0, int c,
                                            int lane, unsigned (*Xb)[64 * 16]) {
    const int m = lane & 15, q = lane >> 4;
    const int tt = c * 64 + q * 16;
    f32x4 v[4];
    if (tt < SEQT) {
        const float* src = input + (size_t)(r0 + m) * SEQT + tt;
#pragma unroll
        for (int p = 0; p < 4; ++p) v[p] = *(const f32x4*)(src + 4 * p);
    } else {
#pragma unroll
        for (int p = 0; p < 4; ++p) v[p] = (f32x4){0.f, 0.f, 0.f, 0.f};
    }
#pragma unroll
    for (int p = 0; p < 4; ++p)
#pragma unroll
        for (int j = 0; j < 4; ++j)
            Xb[c & 1][(q * 16 + p * 4 + j) * 16 + m] = pack_hilo(v[p][j]);
}

__global__ void __launch_bounds__(256)
__attribute__((amdgpu_waves_per_eu(1)))
lstm_fused_kernel(const float* __restrict__ input,
                  const float* __restrict__ W_ih1,
                  const float* __restrict__ W_hh1,
                  const float* __restrict__ b_ih1,
                  const float* __restrict__ b_hh1,
                  const float* __restrict__ W_ih3,
                  const float* __restrict__ W_hh3,
                  const float* __restrict__ b_ih3,
                  const float* __restrict__ b_hh3,
                  float* __restrict__ out) {
    const int t = threadIdx.x;
    const int w = t >> 6;          // wave 0..3
    const int lane = t & 63;
    const int iloc = lane & 15, kq = lane >> 4;
    const int r0 = blockIdx.x * MROW;

    __shared__ short Hst[2][MROW * PADK];      // staged h/x/bias rows, parity dbuf
    __shared__ float C1buf[2][MROW * 52];      // raw f32 c1 (permuted u), parity dbuf
    __shared__ float Obuf[2][MROW * OSTR];     // c3 chunks
    __shared__ unsigned Xbuf[2][64 * 16];      // packed x hi/lo, 64-step chunks

    // tile assignment: w0 {0-3} SL0, w2 {4-7} SL1 + x, w3 {8-11} SL2,
    // w1 {12} + LSTM3 (straggler-trimmed)
    const int NT = (w == 1) ? 1 : 4;
    const int tb = (w == 0) ? 0 : (w == 1) ? 12 : (w == 2) ? 4 : 8;

    // ---- gate-row weight fragments (A-operand, permuted map, exp2-scaled) ----
    s16x8 Wfr[4][5];
#pragma unroll
    for (int i = 0; i < 4; ++i) {
        if (i < NT) {
            const int np = (tb + i) * 16 + iloc;
            const int u_r = np >> 2, g_r = np & 3;
            const int n = g_r * H1 + u_r;
            const bool vr = (u_r < H1);
            const float sc = (g_r == 2) ? -L2E2 : -L2E;
#pragma unroll
            for (int kt = 0; kt < 5; ++kt) {
                s16x8 bf;
#pragma unroll
                for (int j = 0; j < 8; ++j)
                    bf[j] = f2bf(aval(W_hh1, W_ih1, b_ih1, b_hh1, n, sc, vr,
                                      kt * 32 + kq * 8 + j));
                Wfr[i][kt] = bf;
            }
        }
    }

    // ---- wave 1: LSTM3 constants (log2-scaled). lane (m,g3) ----
    const int g3 = lane >> 4;
    const float scg3 = (g3 == 2) ? L2E2 : -L2E;   // kg * log2e
    float Wz[52];
    if (w == 1) {
#pragma unroll
        for (int p = 0; p < 52; ++p) {
            const int u = (p < 48) ? (16 * (p >> 4) + 4 * (p & 3) + ((p >> 2) & 3))
                                   : p;
            Wz[p] = (u < H1) ? scg3 * W_ih3[g3 * H1 + u] : 0.f;
        }
    }
    const float whh3g = scg3 * W_hh3[g3];
    const float b3g = scg3 * (b_ih3[g3] + b_hh3[g3]);
    // activation form: act = bg + ag * rcp(exp2(pre)+1), pre already scaled
    const float ag = (g3 == 2) ? -2.f : 1.f;
    const float bg = (g3 == 2) ? 1.f : 0.f;

    // ---- LDS init ----
    for (int idx = t; idx < 2 * MROW * PADK; idx += 256)
        ((short*)Hst)[idx] = 0;
    for (int idx = t; idx < 2 * MROW * 52; idx += 256)
        ((float*)C1buf)[idx] = 0.f;
    __syncthreads();   // zeros before targeted writes
    if (t < MROW) {
        const int m = t;
#pragma unroll
        for (int p = 0; p < 2; ++p) {
            Hst[p][m * PADK + 156] = (short)0x3F80;   // 1.0 (bias cols)
            Hst[p][m * PADK + 157] = (short)0x3F80;
        }
        const float x0 = input[(size_t)(r0 + m) * SEQT];
        const unsigned xp = pack_hilo(x0);
        Hst[1][m * PADK + 102] = (short)xp;   // window 0 reads parity 1
        Hst[1][m * PADK + 103] = (short)(xp >> 16);
        Hst[1][m * PADK + 155] = (short)xp;
    }
    if (w == 1) {                 // prefill x chunks 0 and 1 (w2 reads after barrier)
        xchunk_fill(input, r0, 0, lane, Xbuf);
        xchunk_fill(input, r0, 1, lane, Xbuf);
    }
    float c1st[4] = {0.f, 0.f, 0.f, 0.f};
    float h3 = 0.f, c3 = 0.f;   // LSTM3 state (wave 1, lanes 0..15 valid)
    float h3b = 0.f;            // h3 broadcast across wave-1 lanes (per m)

#pragma unroll 1
    for (int ts = 0; ts <= SEQT; ++ts) {
        __syncthreads();
        const int rb = (ts + 1) & 1, wb = ts & 1;

        // ---- reads first: LDS read latency overlaps the rest of the step ----
        s16x8 hf[5];
        if (ts < SEQT) {
#pragma unroll
            for (int kt = 0; kt < 5; ++kt)
                hf[kt] = *(const s16x8*)&Hst[rb][iloc * PADK + kt * 32 + kq * 8];
        }
        f32x4 c1v[13];
        if (w == 1 && ts >= 1) {
            const float* cr = &C1buf[rb][(lane & 15) * 52];
#pragma unroll
            for (int j = 0; j < 13; ++j)
                c1v[j] = *(const f32x4*)(cr + 4 * j);
        }

        // ---- coalesced dump of finished 64-chunk ----
        if (ts >= 65 && (ts & 63) == 1) {
            const int c = (ts >> 6) - 1;
#pragma unroll
            for (int rep = 0; rep < 4; ++rep) {
                const int row = w + 4 * rep;
                out[(size_t)(r0 + row) * SEQT + c * 64 + lane] =
                    Obuf[c & 1][row * OSTR + lane];
            }
        }

        // ---- x chunk prefetch: issue loads early (store at step bottom) ----
        const bool fill = (w == 1) && (ts < SEQT) && ((ts & 63) == 0) &&
                          (ts >= 64) && ((ts >> 6) < 31);
        const int fc = (ts >> 6) + 1;
        f32x4 xv[4];
        if (fill) {
            const int fm = lane & 15, fq = lane >> 4;
            const int tt = fc * 64 + fq * 16;
            if (tt < SEQT) {
                const float* src = input + (size_t)(r0 + fm) * SEQT + tt;
#pragma unroll
                for (int p = 0; p < 4; ++p) xv[p] = *(const f32x4*)(src + 4 * p);
            } else {
#pragma unroll
                for (int p = 0; p < 4; ++p) xv[p] = (f32x4){0.f, 0.f, 0.f, 0.f};
            }
        }

        if (ts < SEQT) {
            short* Hw = &Hst[wb][0];
            float* C1w = &C1buf[wb][0];
            if (w == 0) {
                run_tiles<0, 4>(Wfr, hf, c1st, Hw, C1w, iloc, kq);
            } else if (w == 2) {
                // x staging for step ts+1 (cols 102/103/155) — off the straggler
                const int t1 = ts + 1;
                if (t1 < SEQT) {
                    const int m2 = lane & 15;
                    const unsigned pv = Xbuf[(t1 >> 6) & 1][(t1 & 63) * 16 + m2];
                    *(unsigned*)&Hw[m2 * PADK + 102] = pv;
                    Hw[m2 * PADK + 155] = (short)pv;
                }
                run_tiles<1, 4>(Wfr, hf, c1st, Hw, C1w, iloc, kq);
            } else if (w == 3) {
                run_tiles<2, 4>(Wfr, hf, c1st, Hw, C1w, iloc, kq);
            } else {
                run_tiles<3, 1>(Wfr, hf, c1st, Hw, C1w, iloc, kq);
            }
        }

        // ---- LSTM3 for step ts-1 (wave 1, AFTER its tile: c1v latency hidden).
        //      8-acc dot + shfl gate gather (no LDS roundtrip). ----
        if (w == 1 && ts >= 1) {
            float d0a = 0.f, d1a = 0.f, d2a = 0.f, d3a = 0.f;
            float d0b = 0.f, d1b = 0.f, d2b = 0.f, d3b = 0.f;
#pragma unroll
            for (int j = 0; j < 13; ++j) {
                if ((j & 1) == 0) {
                    d0a = fmaf(Wz[4 * j + 0], c1v[j][0], d0a);
                    d1a = fmaf(Wz[4 * j + 1], c1v[j][1], d1a);
                    d2a = fmaf(Wz[4 * j + 2], c1v[j][2], d2a);
                    d3a = fmaf(Wz[4 * j + 3], c1v[j][3], d3a);
                } else {
                    d0b = fmaf(Wz[4 * j + 0], c1v[j][0], d0b);
                    d1b = fmaf(Wz[4 * j + 1], c1v[j][1], d1b);
                    d2b = fmaf(Wz[4 * j + 2], c1v[j][2], d2b);
                    d3b = fmaf(Wz[4 * j + 3], c1v[j][3], d3b);
                }
            }
            const float z = ((d0a + d0b) + (d1a + d1b)) +
                            ((d2a + d2b) + (d3a + d3b));
            const float pre = z + fmaf(whh3g, h3b, b3g);
            const float act = bg + ag * fastrcp(EXP2F(pre) + 1.f);
            // gather the 4 gate activations to lanes 0..15 via shfl_xor (exact)
            const float act1 = __shfl_xor(act, 16, 64);
            const float act2 = __shfl_xor(act, 32, 64);
            const float act3 = __shfl_xor(act, 48, 64);
            const int s = ts - 1;
            if (lane < MROW) {   // lanes<16: act=i, act1=f, act2=g, act3=o
                c3 = act1 * c3 + act * act2;
                h3 = act3 * tanhfast(c3);
                Obuf[(s >> 6) & 1][lane * OSTR + (s & 63)] = c3;
            }
            h3b = __shfl(h3, lane & 15, 64);
        }

        // ---- x chunk prefetch: pack + store (loads had the step to land) ----
        if (fill) {
            const int fm = lane & 15, fq = lane >> 4;
#pragma unroll
            for (int p = 0; p < 4; ++p)
#pragma unroll
                for (int j = 0; j < 4; ++j)
                    Xbuf[fc & 1][(fq * 16 + p * 4 + j) * 16 + fm] =
                        pack_hilo(xv[p][j]);
        }
    }

    __syncthreads();
    // tail: steps 1984..1999 (chunk 31, parity 1)
    {
        const int row = t >> 4, pos = t & 15;
        out[(size_t)(r0 + row) * SEQT + 1984 + pos] = Obuf[1][row * OSTR + pos];
    }
}

extern "C" void kernel_launch(void* const* d_in, const int* in_sizes, int n_in,
                              void* d_out, int out_size, void* d_ws, size_t ws_size,
                              hipStream_t stream) {
    const float* input = (const float*)d_in[0];
    const float* W_ih1 = (const float*)d_in[1];
    const float* W_hh1 = (const float*)d_in[2];
    const float* b_ih1 = (const float*)d_in[3];
    const float* b_hh1 = (const float*)d_in[4];
    const float* W_ih3 = (const float*)d_in[5];
    const float* W_hh3 = (const float*)d_in[6];
    const float* b_ih3 = (const float*)d_in[7];
    const float* b_hh3 = (const float*)d_in[8];
    float* out = (float*)d_out;

    lstm_fused_kernel<<<NBLK, 256, 0, stream>>>(
        input, W_ih1, W_hh1, b_ih1, b_hh1, W_ih3, W_hh3, b_ih3, b_hh3, out);
}